// Round 1
// baseline (115.170 us; speedup 1.0000x reference)
//
#include <hip/hip_runtime.h>
#include <math.h>

#define ECE_N_BINS 10
#define ECE_C 128

// ws layout (floats): [0..9] counts, [10..19] conf_sum, [20..29] acc_sum

__global__ __launch_bounds__(256) void ece_main_kernel(
    const float* __restrict__ logits,
    const int*   __restrict__ labels,
    float*       __restrict__ ws,
    int n_rows)
{
    __shared__ float s_bins[3 * ECE_N_BINS];
    const int tid = threadIdx.x;
    if (tid < 3 * ECE_N_BINS) s_bins[tid] = 0.0f;
    __syncthreads();

    const int lane16         = tid & 15;       // 16 lanes cooperate on one row
    const int row_in_block   = tid >> 4;       // 16 rows per block iteration
    const int rows_per_block = blockDim.x >> 4;

    for (long long row = (long long)blockIdx.x * rows_per_block + row_in_block;
         row < (long long)n_rows;
         row += (long long)gridDim.x * rows_per_block)
    {
        const float4* rp = (const float4*)(logits + row * (long long)ECE_C);
        float4 a = rp[lane16 * 2 + 0];
        float4 b = rp[lane16 * 2 + 1];

        // in-lane max/argmax over 8 contiguous values (first occurrence wins)
        const int base = lane16 * 8;
        float v = a.x; int idx = base;
        if (a.y > v) { v = a.y; idx = base + 1; }
        if (a.z > v) { v = a.z; idx = base + 2; }
        if (a.w > v) { v = a.w; idx = base + 3; }
        if (b.x > v) { v = b.x; idx = base + 4; }
        if (b.y > v) { v = b.y; idx = base + 5; }
        if (b.w > v || b.z > v) { // cheap pre-filter not valid for argmax order; do exact below
    }
        // exact order for indices 4..7 handled above for b.x; redo b.y/z/w exactly:
        // (kept strict-> ordering: earlier index wins ties)
        if (b.y > v) { v = b.y; idx = base + 5; }
        if (b.z > v) { v = b.z; idx = base + 6; }
        if (b.w > v) { v = b.w; idx = base + 7; }

        // butterfly reduce across the 16-lane group: max value, then min index on ties
        #pragma unroll
        for (int m = 1; m < 16; m <<= 1) {
            float ov  = __shfl_xor(v,   m, 16);
            int   oid = __shfl_xor(idx, m, 16);
            if (ov > v || (ov == v && oid < idx)) { v = ov; idx = oid; }
        }

        if (lane16 == 0 && v > 0.0f) {   // valid = conf > 0
            int bin = (int)ceilf(v * (float)ECE_N_BINS) - 1;
            bin = max(0, min(ECE_N_BINS - 1, bin));
            float acc = (idx == labels[row]) ? 1.0f : 0.0f;
            atomicAdd(&s_bins[bin],                  1.0f);
            atomicAdd(&s_bins[ECE_N_BINS + bin],     v);
            atomicAdd(&s_bins[2 * ECE_N_BINS + bin], acc);
        }
    }

    __syncthreads();
    if (tid < 3 * ECE_N_BINS) {
        float val = s_bins[tid];
        if (val != 0.0f) atomicAdd(&ws[tid], val);
    }
}

__global__ void ece_final_kernel(const float* __restrict__ ws,
                                 float* __restrict__ out,
                                 float inv_n)
{
    if (threadIdx.x == 0) {
        float ece = 0.0f;
        #pragma unroll
        for (int b = 0; b < ECE_N_BINS; ++b) {
            float cnt = ws[b];
            if (cnt > 0.0f) {
                float avg_conf = ws[ECE_N_BINS + b]     / cnt;
                float avg_acc  = ws[2 * ECE_N_BINS + b] / cnt;
                ece += fabsf(avg_conf - avg_acc) * cnt * inv_n;
            }
        }
        out[0] = ece;
    }
}

extern "C" void kernel_launch(void* const* d_in, const int* in_sizes, int n_in,
                              void* d_out, int out_size, void* d_ws, size_t ws_size,
                              hipStream_t stream)
{
    const float* logits = (const float*)d_in[0];
    const int*   labels = (const int*)d_in[1];
    float* out = (float*)d_out;
    float* ws  = (float*)d_ws;

    const int n_rows = in_sizes[1];            // labels count = N

    hipMemsetAsync(ws, 0, 3 * ECE_N_BINS * sizeof(float), stream);

    const int block = 256;
    const int rows_per_block = block / 16;     // 16
    int grid = (n_rows + rows_per_block - 1) / rows_per_block;
    if (grid > 2048) grid = 2048;              // grid-stride the rest

    ece_main_kernel<<<grid, block, 0, stream>>>(logits, labels, ws, n_rows);
    ece_final_kernel<<<1, 64, 0, stream>>>(ws, out, 1.0f / (float)n_rows);
}